// Round 1
// baseline (1418.820 us; speedup 1.0000x reference)
//
#include <hip/hip_runtime.h>
#include <cstdint>
#include <cstddef>

// ---------------- types / helpers ----------------
typedef _Float16 f16;
typedef f16 f16x8 __attribute__((ext_vector_type(8)));
typedef float f32x4 __attribute__((ext_vector_type(4)));

#define MFMA(a,b,c) __builtin_amdgcn_mfma_f32_16x16x32_f16(a,b,c,0,0,0)

__device__ __forceinline__ float sigm(float x){ return 1.f/(1.f+__expf(-x)); }
__device__ __forceinline__ float tanh_f(float x){
  float a = __expf(-2.f*fabsf(x));
  float t = (1.f-a)/(1.f+a);
  return x >= 0.f ? t : -t;
}
__device__ __forceinline__ uint16_t f2bf(float f){
  uint32_t u = __float_as_uint(f);
  return (uint16_t)((u + 0x7fffu + ((u>>16)&1u)) >> 16);
}
__device__ __forceinline__ float bf2f(uint16_t h){
  return __uint_as_float(((uint32_t)h) << 16);
}

// ---------------- prep: weights repack, idx, h init ----------------
// BgT layout [4 groups][256 j][352 k] fp16.
//  k 0..95 = x-part (w_ih cols, valid k<76), k 96..351 = h-part (w_hh cols, valid kh<252)
//  group 0=r (rows j), 1=z (rows 252+j), 2=inn (w_ih rows 504+j, h-part zero),
//  3=hn (w_hh rows 504+j, x-part zero). j>=252 -> zero.
__global__ __launch_bounds__(256) void k_prep(
    const float* __restrict__ w_ih, const float* __restrict__ w_hh,
    const float* __restrict__ b_ih, const float* __restrict__ b_hh,
    const float* __restrict__ h0, const int* __restrict__ slen,
    const float* __restrict__ wq, const float* __restrict__ wk,
    const float* __restrict__ gcn_w,
    f16* __restrict__ BgT, f16* __restrict__ wq16, f16* __restrict__ wk16,
    f16* __restrict__ gw16, float* __restrict__ biasc, int* __restrict__ idx,
    float* __restrict__ h32A, f16* __restrict__ h16A)
{
  int id = blockIdx.x*256 + threadIdx.x;
  if (id < 360448){ // BgT: (g*256+j)*352+k
    int g = id / (256*352); int rem = id % (256*352);
    int j = rem / 352; int k = rem % 352;
    float v = 0.f;
    if (j < 252){
      if (k < 96){
        if (k < 76 && g != 3){
          int row = (g==2) ? (504+j) : (g*252+j);
          v = w_ih[row*76 + k];
        }
      } else {
        int kh = k - 96;
        if (kh < 252 && g != 2){
          int row = (g==3) ? (504+j) : (g*252+j);
          v = w_hh[row*252 + kh];
        }
      }
    }
    BgT[id] = (f16)v;
    return;
  }
  id -= 360448;
  if (id < 65536){ wq16[id] = (f16)wq[id]; return; }
  id -= 65536;
  if (id < 65536){ wk16[id] = (f16)wk[id]; return; }
  id -= 65536;
  if (id < 65536){ int j = id >> 8, d = id & 255; gw16[id] = (f16)gcn_w[d*256 + j]; return; }
  id -= 65536;
  if (id < 1008){
    int g = id / 252, j = id % 252; float v;
    if (g==0) v = b_ih[j] + b_hh[j];
    else if (g==1) v = b_ih[252+j] + b_hh[252+j];
    else if (g==2) v = b_ih[504+j];
    else v = b_hh[504+j];
    biasc[id] = v; return;
  }
  id -= 1008;
  if (id < 4096){
    int s = slen[id] - 1; s = s < 0 ? 0 : (s > 47 ? 47 : s);
    idx[id] = s; return;
  }
  id -= 4096;
  if (id < 4096*252){ h32A[id] = h0[id % 252]; return; }
  id -= 4096*252;
  if (id < 4096*256){ int j = id & 255; h16A[id] = (j < 252) ? (f16)h0[j] : (f16)0.f; return; }
}

// ---------------- GRU fused step ----------------
// grid (128, 8): BM=32 rows, JB=32 gate-columns; 4 waves: mi=wave&1, ji=wave>>1
__global__ __launch_bounds__(256) void k_gru(
    const float* __restrict__ x, const f16* __restrict__ h16i,
    const float* __restrict__ h32i, const f16* __restrict__ BgT,
    const float* __restrict__ biasc, const int* __restrict__ idxp,
    float* __restrict__ h32o, f16* __restrict__ h16o,
    float* __restrict__ xstar, int t)
{
  int lane = threadIdx.x & 63, wv = threadIdx.x >> 6;
  int l16 = lane & 15, lq = lane >> 4;
  int mi = wv & 1, ji = wv >> 1;
  int nb = blockIdx.x * 32;
  int jb = blockIdx.y * 32;
  int row0 = nb + mi*16 + l16;
  int jcol = jb + ji*16 + l16;
  const f16* b0p = BgT + (size_t)(0*256 + jcol)*352;
  const f16* b1p = BgT + (size_t)(1*256 + jcol)*352;
  const f16* b2p = BgT + (size_t)(2*256 + jcol)*352;
  const f16* b3p = BgT + (size_t)(3*256 + jcol)*352;
  f32x4 z4 = {0.f,0.f,0.f,0.f};
  f32x4 accR = z4, accZ = z4, accI = z4, accH = z4;
  const float* xp = x + ((size_t)row0*48 + (size_t)t)*76;
  const f16* hp = h16i + (size_t)row0*256;
  #pragma unroll
  for (int ks = 0; ks < 11; ++ks){
    int koff = ks*32 + lq*8;
    f16x8 a;
    if (ks < 3){
      #pragma unroll
      for (int e = 0; e < 8; ++e){
        int k = koff + e;
        f16 av = (f16)0.f;
        if (k < 76) av = (f16)xp[k];
        a[e] = av;
      }
    } else {
      a = *(const f16x8*)(hp + (koff - 96));
    }
    f16x8 br = *(const f16x8*)(b0p + koff);
    f16x8 bz = *(const f16x8*)(b1p + koff);
    accR = MFMA(a, br, accR);
    accZ = MFMA(a, bz, accZ);
    if (ks < 3){
      f16x8 bi = *(const f16x8*)(b2p + koff);
      accI = MFMA(a, bi, accI);
    } else {
      f16x8 bh = *(const f16x8*)(b3p + koff);
      accH = MFMA(a, bh, accH);
    }
  }
  if (jcol < 252){
    float bR = biasc[jcol], bZ = biasc[252+jcol], bI = biasc[504+jcol], bH = biasc[756+jcol];
    #pragma unroll
    for (int r = 0; r < 4; ++r){
      int n = nb + mi*16 + lq*4 + r;
      float rr = sigm(accR[r] + bR);
      float zz = sigm(accZ[r] + bZ);
      float ng = tanh_f(accI[r] + bI + rr*(accH[r] + bH));
      float hold = h32i[(size_t)n*252 + jcol];
      float hnew = (1.f - zz)*ng + zz*hold;
      h32o[(size_t)n*252 + jcol] = hnew;
      h16o[(size_t)n*256 + jcol] = (f16)hnew;
      if (idxp[n] == t) xstar[(size_t)n*256 + jcol] = hnew;
    }
  }
}

// ---------------- x_star assembly (demo cols) + fp16 copy ----------------
__global__ __launch_bounds__(256) void k_xstar(const float* __restrict__ x_demo,
    float* __restrict__ xs32, f16* __restrict__ xs16)
{
  int id = blockIdx.x*256 + threadIdx.x;
  int n = id >> 8, c = id & 255;
  float v;
  if (c < 252) v = xs32[id];
  else v = x_demo[n*4 + (c - 252)];
  xs32[id] = v;
  xs16[id] = (f16)v;
}

// ---------------- q/k projections ----------------
// MODE 0: out = (xs@wq^T + bq) * wo[head]/8 ; MODE 1: out = xs@wk^T + bk
template<int MODE>
__global__ __launch_bounds__(256) void k_proj(const f16* __restrict__ xs16,
    const f16* __restrict__ w16, const float* __restrict__ bias,
    const float* __restrict__ wo, f16* __restrict__ out16)
{
  int lane = threadIdx.x & 63, wv = threadIdx.x >> 6;
  int l16 = lane & 15, lq = lane >> 4;
  int nb = blockIdx.x * 64;
  int ocol = blockIdx.y*64 + wv*16 + l16;
  f32x4 z4 = {0.f,0.f,0.f,0.f};
  f32x4 acc[4] = {z4,z4,z4,z4};
  #pragma unroll
  for (int ks = 0; ks < 8; ++ks){
    f16x8 b = *(const f16x8*)(w16 + (size_t)ocol*256 + ks*32 + lq*8);
    #pragma unroll
    for (int mi = 0; mi < 4; ++mi){
      f16x8 a = *(const f16x8*)(xs16 + (size_t)(nb + mi*16 + l16)*256 + ks*32 + lq*8);
      acc[mi] = MFMA(a, b, acc[mi]);
    }
  }
  float badd = bias[ocol];
  float scale = (MODE == 0) ? wo[ocol >> 6]*0.125f : 1.f;
  #pragma unroll
  for (int mi = 0; mi < 4; ++mi)
  #pragma unroll
  for (int r = 0; r < 4; ++r){
    int n = nb + mi*16 + lq*4 + r;
    float v = acc[mi][r] + badd;
    if (MODE == 0) v *= scale;
    out16[(size_t)n*256 + ocol] = (f16)v;
  }
}

// ---------------- scores GEMM (bf16 store) ----------------
__global__ __launch_bounds__(256) void k_scores(const f16* __restrict__ qf,
    const f16* __restrict__ kf, uint16_t* __restrict__ sco)
{
  int lane = threadIdx.x & 63, wv = threadIdx.x >> 6;
  int l16 = lane & 15, lq = lane >> 4;
  int nb = blockIdx.x * 64;
  int mcol = blockIdx.y*64 + wv*16 + l16;
  f32x4 z4 = {0.f,0.f,0.f,0.f};
  f32x4 acc[4] = {z4,z4,z4,z4};
  #pragma unroll
  for (int ks = 0; ks < 8; ++ks){
    f16x8 b = *(const f16x8*)(kf + (size_t)mcol*256 + ks*32 + lq*8);
    #pragma unroll
    for (int mi = 0; mi < 4; ++mi){
      f16x8 a = *(const f16x8*)(qf + (size_t)(nb + mi*16 + l16)*256 + ks*32 + lq*8);
      acc[mi] = MFMA(a, b, acc[mi]);
    }
  }
  #pragma unroll
  for (int mi = 0; mi < 4; ++mi)
  #pragma unroll
  for (int r = 0; r < 4; ++r){
    int n = nb + mi*16 + lq*4 + r;
    sco[((size_t)n << 12) + mcol] = f2bf(acc[mi][r]);
  }
}

// ---------------- softmax row stats ----------------
__global__ __launch_bounds__(256) void k_stats(const uint16_t* __restrict__ sco,
    float* __restrict__ rmax, float* __restrict__ rrs)
{
  int n = blockIdx.x;
  int lane = threadIdx.x & 63, wv = threadIdx.x >> 6;
  const uint16_t* row = sco + ((size_t)n << 12);
  int base = threadIdx.x * 16;
  const uint4* p = (const uint4*)(row + base);
  uint4 w0 = p[0], w1 = p[1];
  uint32_t ws_[8] = {w0.x,w0.y,w0.z,w0.w,w1.x,w1.y,w1.z,w1.w};
  float v[16];
  #pragma unroll
  for (int i = 0; i < 8; ++i){
    v[2*i]   = bf2f((uint16_t)(ws_[i] & 0xffffu));
    v[2*i+1] = bf2f((uint16_t)(ws_[i] >> 16));
  }
  float mx = v[0];
  #pragma unroll
  for (int i = 1; i < 16; ++i) mx = fmaxf(mx, v[i]);
  #pragma unroll
  for (int o = 32; o >= 1; o >>= 1) mx = fmaxf(mx, __shfl_xor(mx, o));
  __shared__ float red[4];
  if (lane == 0) red[wv] = mx;
  __syncthreads();
  mx = fmaxf(fmaxf(red[0], red[1]), fmaxf(red[2], red[3]));
  float s = 0.f;
  #pragma unroll
  for (int i = 0; i < 16; ++i) s += __expf(v[i] - mx);
  #pragma unroll
  for (int o = 32; o >= 1; o >>= 1) s += __shfl_xor(s, o);
  __shared__ float red2[4];
  if (lane == 0) red2[wv] = s;
  __syncthreads();
  if (threadIdx.x == 0){
    float tot = red2[0] + red2[1] + red2[2] + red2[3];
    rmax[n] = mx;
    rrs[n] = 1.f / tot;
  }
}

// ---------------- adjacency flags (bit0=adj, bit1=adj_aug) ----------------
__global__ __launch_bounds__(256) void k_flags(const uint16_t* __restrict__ sco,
    const float* __restrict__ rmax, const float* __restrict__ rrs,
    const float* __restrict__ mask_edge, const float* __restrict__ phip,
    uint8_t* __restrict__ flags)
{
  int n = blockIdx.y;
  int m0 = (blockIdx.x*256 + threadIdx.x) * 8;
  float bm = rmax[n], rs = rrs[n], phi = phip[0];
  const uint4* p = (const uint4*)(sco + ((size_t)n << 12) + m0);
  uint4 wv = p[0];
  uint32_t ws_[4] = {wv.x, wv.y, wv.z, wv.w};
  uint32_t by[8]; bool any = false;
  #pragma unroll
  for (int i = 0; i < 4; ++i){
    float v0 = bf2f((uint16_t)(ws_[i] & 0xffffu));
    float v1 = bf2f((uint16_t)(ws_[i] >> 16));
    float a0 = __expf(v0 - bm) * rs;
    float a1 = __expf(v1 - bm) * rs;
    by[2*i]   = (a0 >= phi && (m0 + 2*i)     != n) ? 1u : 0u;
    by[2*i+1] = (a1 >= phi && (m0 + 2*i + 1) != n) ? 1u : 0u;
    any = any || by[2*i] || by[2*i+1];
  }
  if (any){
    #pragma unroll
    for (int e = 0; e < 8; ++e)
      if (by[e]){ if (mask_edge[((size_t)n << 12) + m0 + e] >= 0.1f) by[e] |= 2u; }
  }
  uint2 pk;
  pk.x = by[0] | (by[1] << 8) | (by[2] << 16) | (by[3] << 24);
  pk.y = by[4] | (by[5] << 8) | (by[6] << 16) | (by[7] << 24);
  *(uint2*)(flags + ((size_t)n << 12) + m0) = pk;
}

// ---------------- degrees / dinv ----------------
__global__ __launch_bounds__(256) void k_deg(const uint8_t* __restrict__ flags,
    float* __restrict__ sadj, float* __restrict__ dinv, float* __restrict__ dinva)
{
  int n = blockIdx.x;
  int lane = threadIdx.x & 63, wv = threadIdx.x >> 6;
  const uint4* row = (const uint4*)(flags + ((size_t)n << 12));
  uint4 w = row[threadIdx.x];
  int c0 = __popc(w.x & 0x01010101u) + __popc(w.y & 0x01010101u)
         + __popc(w.z & 0x01010101u) + __popc(w.w & 0x01010101u);
  int c1 = __popc(w.x & 0x02020202u) + __popc(w.y & 0x02020202u)
         + __popc(w.z & 0x02020202u) + __popc(w.w & 0x02020202u);
  float f0 = (float)c0, f1 = (float)c1;
  #pragma unroll
  for (int o = 32; o >= 1; o >>= 1){ f0 += __shfl_xor(f0, o); f1 += __shfl_xor(f1, o); }
  __shared__ float r0[4], r1[4];
  if (lane == 0){ r0[wv] = f0; r1[wv] = f1; }
  __syncthreads();
  if (threadIdx.x == 0){
    float d0 = r0[0]+r0[1]+r0[2]+r0[3];
    float d1 = r1[0]+r1[1]+r1[2]+r1[3];
    sadj[n] = d0;
    dinv[n]  = rsqrtf(1.f + d0);
    dinva[n] = rsqrtf(1.f + d1);
  }
}

// ---------------- xw = xs@gcn_w ; y = dinv*xw (fp16) ----------------
__global__ __launch_bounds__(256) void k_xw_y(const f16* __restrict__ xs16,
    const f16* __restrict__ gw16, const float* __restrict__ dinv,
    const float* __restrict__ dinva, f16* __restrict__ y16, f16* __restrict__ ya16)
{
  int lane = threadIdx.x & 63, wv = threadIdx.x >> 6;
  int l16 = lane & 15, lq = lane >> 4;
  int nb = blockIdx.x * 64;
  int jcol = blockIdx.y*64 + wv*16 + l16;
  f32x4 z4 = {0.f,0.f,0.f,0.f};
  f32x4 acc[4] = {z4,z4,z4,z4};
  #pragma unroll
  for (int ks = 0; ks < 8; ++ks){
    f16x8 b = *(const f16x8*)(gw16 + (size_t)jcol*256 + ks*32 + lq*8);
    #pragma unroll
    for (int mi = 0; mi < 4; ++mi){
      f16x8 a = *(const f16x8*)(xs16 + (size_t)(nb + mi*16 + l16)*256 + ks*32 + lq*8);
      acc[mi] = MFMA(a, b, acc[mi]);
    }
  }
  #pragma unroll
  for (int mi = 0; mi < 4; ++mi)
  #pragma unroll
  for (int r = 0; r < 4; ++r){
    int n = nb + mi*16 + lq*4 + r;
    float v = acc[mi][r];
    y16[(size_t)n*256 + jcol]  = (f16)(dinv[n]*v);
    ya16[(size_t)n*256 + jcol] = (f16)(dinva[n]*v);
  }
}

// ---------------- GCN: z[n] = dinv[n]*(y[n] + sum_{adj} y[m]) + b ----------------
__global__ __launch_bounds__(256) void k_zgather(const uint8_t* __restrict__ flags,
    const f16* __restrict__ y16, const f16* __restrict__ ya16,
    const float* __restrict__ dinv, const float* __restrict__ dinva,
    const float* __restrict__ gcn_b, float* __restrict__ z32, float* __restrict__ za32)
{
  int n = blockIdx.x;
  int aug = blockIdx.y;
  const f16* y = aug ? ya16 : y16;
  int j = threadIdx.x;
  __shared__ uint32_t fl[1024];
  ((uint4*)fl)[threadIdx.x] = ((const uint4*)(flags + ((size_t)n << 12)))[threadIdx.x];
  __syncthreads();
  uint32_t bitm = aug ? 0x02020202u : 0x01010101u;
  float accv = (float)y[((size_t)n << 8) + j];  // self loop
  for (int wd = 0; wd < 1024; ++wd){
    uint32_t f = __builtin_amdgcn_readfirstlane(fl[wd]) & bitm;
    if (f){
      int mb4 = wd * 4;
      if (f & 0x000000ffu) accv += (float)y[((size_t)(mb4+0) << 8) + j];
      if (f & 0x0000ff00u) accv += (float)y[((size_t)(mb4+1) << 8) + j];
      if (f & 0x00ff0000u) accv += (float)y[((size_t)(mb4+2) << 8) + j];
      if (f & 0xff000000u) accv += (float)y[((size_t)(mb4+3) << 8) + j];
    }
  }
  float dv = aug ? dinva[n] : dinv[n];
  float* z = aug ? za32 : z32;
  z[((size_t)n << 8) + j] = dv*accv + gcn_b[j];
}

// ---------------- clustering: qsoft, labels, colsum ----------------
__global__ __launch_bounds__(256) void k_cluster(const float* __restrict__ xs32,
    const float* __restrict__ centers, float* __restrict__ qsoft,
    int* __restrict__ labels, float* __restrict__ colsum)
{
  int nb = blockIdx.x * 16;
  __shared__ float xs[16][256];
  __shared__ float ct[2560];   // transposed [d][k]
  __shared__ float d2s[16][10];
  __shared__ float qs[16][10];
  for (int i = threadIdx.x; i < 16*256; i += 256) xs[i >> 8][i & 255] = xs32[(size_t)nb*256 + i];
  for (int i = threadIdx.x; i < 2560; i += 256){ int k = i >> 8, d = i & 255; ct[d*10 + k] = centers[i]; }
  __syncthreads();
  if (threadIdx.x < 160){
    int r = threadIdx.x / 10, k = threadIdx.x % 10;
    float s = 0.f;
    for (int d = 0; d < 256; ++d){ float df = xs[r][d] - ct[d*10 + k]; s += df*df; }
    d2s[r][k] = s;
  }
  __syncthreads();
  if (threadIdx.x < 16){
    int r = threadIdx.x;
    float un[10]; float tot = 0.f;
    #pragma unroll
    for (int k = 0; k < 10; ++k){ un[k] = 1.f/(1.f + d2s[r][k]); tot += un[k]; }
    float inv = 1.f / tot;
    int best = 0; float bm = un[0];
    #pragma unroll
    for (int k = 1; k < 10; ++k){ if (un[k] > bm){ bm = un[k]; best = k; } }
    labels[nb + r] = best;
    #pragma unroll
    for (int k = 0; k < 10; ++k){ float q = un[k]*inv; qs[r][k] = q; qsoft[(size_t)(nb + r)*10 + k] = q; }
  }
  __syncthreads();
  if (threadIdx.x < 10){
    int k = threadIdx.x; float s = 0.f;
    #pragma unroll
    for (int r = 0; r < 16; ++r) s += qs[r][k];
    atomicAdd(&colsum[k], s);
  }
}

// ---------------- KL loss ----------------
__global__ __launch_bounds__(256) void k_kl(const float* __restrict__ qsoft,
    const float* __restrict__ colsum, float* __restrict__ klsum)
{
  int n = blockIdx.x*256 + threadIdx.x;
  float p[10]; float s = 0.f;
  #pragma unroll
  for (int k = 0; k < 10; ++k){
    float q = qsoft[(size_t)n*10 + k];
    float pu = q*q/colsum[k];
    p[k] = pu; s += pu;
  }
  float inv = 1.f/s; float kl = 0.f;
  #pragma unroll
  for (int k = 0; k < 10; ++k){
    float pk = p[k]*inv;
    float q = qsoft[(size_t)n*10 + k];
    kl += pk*__logf(pk/(q + 1e-6f));
  }
  int lane = threadIdx.x & 63, wv = threadIdx.x >> 6;
  #pragma unroll
  for (int o = 32; o >= 1; o >>= 1) kl += __shfl_xor(kl, o);
  __shared__ float red[4];
  if (lane == 0) red[wv] = kl;
  __syncthreads();
  if (threadIdx.x == 0) atomicAdd(klsum, red[0]+red[1]+red[2]+red[3]);
}

// ---------------- FFN + l2-normalize ----------------
__global__ __launch_bounds__(128) void k_ffn(const float* __restrict__ z32,
    const float* __restrict__ za32, const float* __restrict__ ffn_w,
    const float* __restrict__ ffn_b, f16* __restrict__ zn16, f16* __restrict__ zan16)
{
  int n = blockIdx.x; int aug = blockIdx.y;
  const float* z = (aug ? za32 : z32) + ((size_t)n << 8);
  __shared__ float zr[256];
  zr[threadIdx.x] = z[threadIdx.x];
  zr[threadIdx.x + 128] = z[threadIdx.x + 128];
  __syncthreads();
  int j = threadIdx.x;
  float acc = ffn_b[j];
  #pragma unroll 8
  for (int d = 0; d < 256; ++d) acc += zr[d]*ffn_w[d*128 + j];
  float ss = acc*acc;
  int lane = threadIdx.x & 63, wv = threadIdx.x >> 6;
  #pragma unroll
  for (int o = 32; o >= 1; o >>= 1) ss += __shfl_xor(ss, o);
  __shared__ float sred[2];
  if (lane == 0) sred[wv] = ss;
  __syncthreads();
  float tot = sred[0] + sred[1];
  float rn = 1.f / fmaxf(sqrtf(tot), 1e-12f);
  (aug ? zan16 : zn16)[((size_t)n << 7) + j] = (f16)(acc*rn);
}

// ---------------- contrastive loss partial sums ----------------
// grid (128, 8): 32 rows/block, 512 m per y-chunk; K=128
__global__ __launch_bounds__(256) void k_closs(const f16* __restrict__ zn,
    const f16* __restrict__ zan, const uint8_t* __restrict__ flags,
    const int* __restrict__ labels,
    float* __restrict__ rs1, float* __restrict__ rs2, float* __restrict__ rsA,
    float* __restrict__ rsC, float* __restrict__ rcC, float* __restrict__ rdI,
    float* __restrict__ rdi)
{
  int lane = threadIdx.x & 63;
  int ji = threadIdx.x >> 6;
  int l16 = lane & 15, lq = lane >> 4;
  int nb = blockIdx.x * 32;
  int mstart = blockIdx.y * 512;
  f16x8 A[2][4];
  #pragma unroll
  for (int mi = 0; mi < 2; ++mi)
  #pragma unroll
  for (int ks = 0; ks < 4; ++ks)
    A[mi][ks] = *(const f16x8*)(zn + (size_t)(nb + mi*16 + l16)*128 + ks*32 + lq*8);
  int labn[8];
  #pragma unroll
  for (int i = 0; i < 8; ++i) labn[i] = labels[nb + (i >> 2)*16 + lq*4 + (i & 3)];
  float a1[8]={}, a2[8]={}, aA[8]={}, aC[8]={}, aCc[8]={}, adI[8]={}, adi[8]={};
  for (int tile = 0; tile < 8; ++tile){
    int mcol = mstart + tile*64 + ji*16 + l16;
    int labm = labels[mcol];
    f32x4 z4 = {0.f,0.f,0.f,0.f};
    f32x4 acc1[2] = {z4, z4};
    f32x4 acc2[2] = {z4, z4};
    #pragma unroll
    for (int ks = 0; ks < 4; ++ks){
      f16x8 b1 = *(const f16x8*)(zn  + (size_t)mcol*128 + ks*32 + lq*8);
      f16x8 b2 = *(const f16x8*)(zan + (size_t)mcol*128 + ks*32 + lq*8);
      #pragma unroll
      for (int mi = 0; mi < 2; ++mi){
        acc1[mi] = MFMA(A[mi][ks], b1, acc1[mi]);
        acc2[mi] = MFMA(A[mi][ks], b2, acc2[mi]);
      }
    }
    #pragma unroll
    for (int mi = 0; mi < 2; ++mi)
    #pragma unroll
    for (int r = 0; r < 4; ++r){
      int i8 = mi*4 + r;
      int n = nb + mi*16 + lq*4 + r;
      float e1 = __expf(2.f*acc1[mi][r]);
      float e2 = __expf(2.f*acc2[mi][r]);
      uint8_t fl = flags[((size_t)n << 12) + mcol];
      a1[i8] += e1; a2[i8] += e2;
      bool adjb = (fl & 1);
      if (adjb) aA[i8] += e1;
      if (!adjb && labn[i8] == labm && n != mcol){ aC[i8] += e1; aCc[i8] += 1.f; }
      if (n == mcol){ adI[i8] += e2; adi[i8] += e1; }
    }
  }
  #pragma unroll
  for (int i = 0; i < 8; ++i){
    #pragma unroll
    for (int o = 1; o < 16; o <<= 1){
      a1[i]  += __shfl_xor(a1[i], o);  a2[i]  += __shfl_xor(a2[i], o);
      aA[i]  += __shfl_xor(aA[i], o);  aC[i]  += __shfl_xor(aC[i], o);
      aCc[i] += __shfl_xor(aCc[i], o); adI[i] += __shfl_xor(adI[i], o);
      adi[i] += __shfl_xor(adi[i], o);
    }
  }
  if (l16 == 0){
    #pragma unroll
    for (int i = 0; i < 8; ++i){
      int n = nb + (i >> 2)*16 + lq*4 + (i & 3);
      atomicAdd(&rs1[n], a1[i]);  atomicAdd(&rs2[n], a2[i]);
      atomicAdd(&rsA[n], aA[i]);  atomicAdd(&rsC[n], aC[i]);
      atomicAdd(&rcC[n], aCc[i]); atomicAdd(&rdI[n], adI[i]);
      atomicAdd(&rdi[n], adi[i]);
    }
  }
}

// ---------------- contrastive loss finalize ----------------
__global__ __launch_bounds__(256) void k_clfinal(const float* __restrict__ rs1,
    const float* __restrict__ rs2, const float* __restrict__ rsA,
    const float* __restrict__ rsC, const float* __restrict__ rcC,
    const float* __restrict__ rdI, const float* __restrict__ rdi,
    const float* __restrict__ sadj, float* __restrict__ clsum)
{
  int n = blockIdx.x*256 + threadIdx.x;
  float pos = rdI[n] + rsA[n] + rsC[n];
  float den = rs1[n] + rs2[n] - rdi[n];
  float cnt = sadj[n] + rcC[n] + 1.f;
  float v = __logf(pos/den)/cnt;
  int lane = threadIdx.x & 63, wv = threadIdx.x >> 6;
  #pragma unroll
  for (int o = 32; o >= 1; o >>= 1) v += __shfl_xor(v, o);
  __shared__ float red[4];
  if (lane == 0) red[wv] = v;
  __syncthreads();
  if (threadIdx.x == 0) atomicAdd(clsum, red[0]+red[1]+red[2]+red[3]);
}

__global__ void k_loss(const float* __restrict__ scal, float* __restrict__ out){
  out[8192] = scal[0]*(1.f/4096.f) - scal[1];
}

// ---------------- output head ----------------
__global__ __launch_bounds__(256) void k_outhead(const float* __restrict__ z32,
    const float* __restrict__ pre_w, const float* __restrict__ pre_b,
    float* __restrict__ out)
{
  int nb = blockIdx.x * 8;
  __shared__ float zr[8][256];
  for (int i = threadIdx.x; i < 2048; i += 256) zr[i >> 8][i & 255] = z32[(size_t)nb*256 + i];
  __syncthreads();
  if (threadIdx.x < 16){
    int r = threadIdx.x >> 1, c = threadIdx.x & 1;
    float s = pre_b[c];
    for (int d = 0; d < 256; ++d) s += zr[r][d]*pre_w[d*2 + c];
    out[(size_t)(nb + r)*2 + c] = s;
  }
}

// ---------------- host launch ----------------
extern "C" void kernel_launch(void* const* d_in, const int* in_sizes, int n_in,
                              void* d_out, int out_size, void* d_ws, size_t ws_size,
                              hipStream_t stream)
{
  const float* x         = (const float*)d_in[0];
  const float* x_demo    = (const float*)d_in[1];
  const int*   slen      = (const int*)d_in[2];
  const float* mask_edge = (const float*)d_in[3];
  const float* w_ih      = (const float*)d_in[4];
  const float* w_hh      = (const float*)d_in[5];
  const float* b_ih      = (const float*)d_in[6];
  const float* b_hh      = (const float*)d_in[7];
  const float* h0        = (const float*)d_in[8];
  const float* wq        = (const float*)d_in[9];
  const float* bq        = (const float*)d_in[10];
  const float* wk        = (const float*)d_in[11];
  const float* bk        = (const float*)d_in[12];
  const float* wo        = (const float*)d_in[13];
  const float* phi       = (const float*)d_in[15];
  const float* centers   = (const float*)d_in[16];
  const float* gcn_w     = (const float*)d_in[17];
  const float* gcn_b     = (const float*)d_in[18];
  const float* ffn_w     = (const float*)d_in[19];
  const float* ffn_b     = (const float*)d_in[20];
  const float* pre_w     = (const float*)d_in[21];
  const float* pre_b     = (const float*)d_in[22];
  float* out = (float*)d_out;

  size_t off = 0;
  char* base = (char*)d_ws;
  auto take = [&](size_t bytes)->void*{
    void* p = base + off;
    off += (bytes + 255) & ~(size_t)255;
    return p;
  };
  float* h32A   = (float*)take((size_t)4096*252*4);
  float* h32B   = (float*)take((size_t)4096*252*4);
  f16*   h16A   = (f16*)take((size_t)4096*256*2);
  f16*   h16B   = (f16*)take((size_t)4096*256*2);
  f16*   BgT    = (f16*)take((size_t)4*256*352*2);
  f16*   wq16   = (f16*)take((size_t)65536*2);
  f16*   wk16   = (f16*)take((size_t)65536*2);
  f16*   gw16   = (f16*)take((size_t)65536*2);
  float* biasc  = (float*)take(1008*4);
  int*   idx    = (int*)take(4096*4);
  float* xs32   = (float*)take((size_t)4096*256*4);
  f16*   xs16   = (f16*)take((size_t)4096*256*2);
  f16*   qf16   = (f16*)take((size_t)4096*256*2);
  f16*   kf16   = (f16*)take((size_t)4096*256*2);
  uint16_t* sco = (uint16_t*)take((size_t)4096*4096*2);
  float* rmax   = (float*)take(4096*4);
  float* rrs    = (float*)take(4096*4);
  uint8_t* flags= (uint8_t*)take((size_t)4096*4096);
  float* sadj   = (float*)take(4096*4);
  float* dinv   = (float*)take(4096*4);
  float* dinva  = (float*)take(4096*4);
  f16*   y16    = (f16*)take((size_t)4096*256*2);
  f16*   ya16   = (f16*)take((size_t)4096*256*2);
  float* z32    = (float*)take((size_t)4096*256*4);
  float* za32   = (float*)take((size_t)4096*256*4);
  f16*   zn16   = (f16*)take((size_t)4096*128*2);
  f16*   zan16  = (f16*)take((size_t)4096*128*2);
  float* qsoft  = (float*)take((size_t)4096*10*4);
  int*   labels = (int*)take(4096*4);
  float* colsum = (float*)take(64);
  float* scal   = (float*)take(64);         // [0]=klsum, [1]=clsum
  float* rsbuf  = (float*)take((size_t)7*4096*4);
  float* rs1 = rsbuf,        *rs2 = rsbuf + 4096, *rsA = rsbuf + 2*4096;
  float* rsC = rsbuf + 3*4096, *rcC = rsbuf + 4*4096;
  float* rdI = rsbuf + 5*4096, *rdi = rsbuf + 6*4096;

  hipMemsetAsync(h16A, 0, (size_t)4096*256*2, stream);
  hipMemsetAsync(h16B, 0, (size_t)4096*256*2, stream);
  hipMemsetAsync(colsum, 0, 64, stream);
  hipMemsetAsync(scal, 0, 64, stream);
  hipMemsetAsync(rsbuf, 0, (size_t)7*4096*4, stream);

  k_prep<<<10325, 256, 0, stream>>>(w_ih, w_hh, b_ih, b_hh, h0, slen, wq, wk, gcn_w,
                                    BgT, wq16, wk16, gw16, biasc, idx, h32A, h16A);

  for (int t = 0; t < 48; ++t){
    const float* hi32 = (t & 1) ? h32B : h32A;
    float*       ho32 = (t & 1) ? h32A : h32B;
    const f16*   hi16 = (t & 1) ? h16B : h16A;
    f16*         ho16 = (t & 1) ? h16A : h16B;
    k_gru<<<dim3(128, 8), 256, 0, stream>>>(x, hi16, hi32, BgT, biasc, idx,
                                            ho32, ho16, xs32, t);
  }
  k_xstar<<<4096, 256, 0, stream>>>(x_demo, xs32, xs16);
  k_proj<0><<<dim3(64, 4), 256, 0, stream>>>(xs16, wq16, bq, wo, qf16);
  k_proj<1><<<dim3(64, 4), 256, 0, stream>>>(xs16, wk16, bk, wo, kf16);
  k_scores<<<dim3(64, 64), 256, 0, stream>>>(qf16, kf16, sco);
  k_stats<<<4096, 256, 0, stream>>>(sco, rmax, rrs);
  k_flags<<<dim3(2, 4096), 256, 0, stream>>>(sco, rmax, rrs, mask_edge, phi, flags);
  k_deg<<<4096, 256, 0, stream>>>(flags, sadj, dinv, dinva);
  k_xw_y<<<dim3(64, 4), 256, 0, stream>>>(xs16, gw16, dinv, dinva, y16, ya16);
  k_zgather<<<dim3(4096, 2), 256, 0, stream>>>(flags, y16, ya16, dinv, dinva, gcn_b, z32, za32);
  k_cluster<<<256, 256, 0, stream>>>(xs32, centers, qsoft, labels, colsum);
  k_kl<<<16, 256, 0, stream>>>(qsoft, colsum, &scal[0]);
  k_ffn<<<dim3(4096, 2), 128, 0, stream>>>(z32, za32, ffn_w, ffn_b, zn16, zan16);
  k_closs<<<dim3(128, 8), 256, 0, stream>>>(zn16, zan16, flags, labels,
                                            rs1, rs2, rsA, rsC, rcC, rdI, rdi);
  k_clfinal<<<16, 256, 0, stream>>>(rs1, rs2, rsA, rsC, rcC, rdI, rdi, sadj, &scal[1]);
  k_loss<<<1, 1, 0, stream>>>(scal, out);
  k_outhead<<<512, 256, 0, stream>>>(z32, pre_w, pre_b, out);

  (void)in_sizes; (void)n_in; (void)out_size; (void)ws_size;
}

// Round 2
// 1036.850 us; speedup vs baseline: 1.3684x; 1.3684x over previous
//
#include <hip/hip_runtime.h>
#include <cstdint>
#include <cstddef>

// ---------------- types / helpers ----------------
typedef _Float16 f16;
typedef f16 f16x8 __attribute__((ext_vector_type(8)));
typedef float f32x4 __attribute__((ext_vector_type(4)));

#define MFMA(a,b,c) __builtin_amdgcn_mfma_f32_16x16x32_f16(a,b,c,0,0,0)

__device__ __forceinline__ float sigm(float x){ return 1.f/(1.f+__expf(-x)); }
__device__ __forceinline__ float tanh_f(float x){
  float a = __expf(-2.f*fabsf(x));
  float t = (1.f-a)/(1.f+a);
  return x >= 0.f ? t : -t;
}
__device__ __forceinline__ uint16_t f2bf(float f){
  uint32_t u = __float_as_uint(f);
  return (uint16_t)((u + 0x7fffu + ((u>>16)&1u)) >> 16);
}
__device__ __forceinline__ float bf2f(uint16_t h){
  return __uint_as_float(((uint32_t)h) << 16);
}

// ---------------- prep: weights repack, idx, h init ----------------
// BgT layout [4 groups][256 j][352 k] fp16.
//  k 0..95 = x-part (w_ih cols, valid k<76), k 96..351 = h-part (w_hh cols, valid kh<252)
//  group 0=r (rows j), 1=z (rows 252+j), 2=inn (w_ih rows 504+j, h-part zero),
//  3=hn (w_hh rows 504+j, x-part zero). j>=252 -> zero.
__global__ __launch_bounds__(256) void k_prep(
    const float* __restrict__ w_ih, const float* __restrict__ w_hh,
    const float* __restrict__ b_ih, const float* __restrict__ b_hh,
    const float* __restrict__ h0, const int* __restrict__ slen,
    const float* __restrict__ wq, const float* __restrict__ wk,
    const float* __restrict__ gcn_w,
    f16* __restrict__ BgT, f16* __restrict__ wq16, f16* __restrict__ wk16,
    f16* __restrict__ gw16, float* __restrict__ biasc, int* __restrict__ idx,
    float* __restrict__ h32A, f16* __restrict__ h16A)
{
  int id = blockIdx.x*256 + threadIdx.x;
  if (id < 360448){ // BgT: (g*256+j)*352+k
    int g = id / (256*352); int rem = id % (256*352);
    int j = rem / 352; int k = rem % 352;
    float v = 0.f;
    if (j < 252){
      if (k < 96){
        if (k < 76 && g != 3){
          int row = (g==2) ? (504+j) : (g*252+j);
          v = w_ih[row*76 + k];
        }
      } else {
        int kh = k - 96;
        if (kh < 252 && g != 2){
          int row = (g==3) ? (504+j) : (g*252+j);
          v = w_hh[row*252 + kh];
        }
      }
    }
    BgT[id] = (f16)v;
    return;
  }
  id -= 360448;
  if (id < 65536){ wq16[id] = (f16)wq[id]; return; }
  id -= 65536;
  if (id < 65536){ wk16[id] = (f16)wk[id]; return; }
  id -= 65536;
  if (id < 65536){ int j = id >> 8, d = id & 255; gw16[id] = (f16)gcn_w[d*256 + j]; return; }
  id -= 65536;
  if (id < 1008){
    int g = id / 252, j = id % 252; float v;
    if (g==0) v = b_ih[j] + b_hh[j];
    else if (g==1) v = b_ih[252+j] + b_hh[252+j];
    else if (g==2) v = b_ih[504+j];
    else v = b_hh[504+j];
    biasc[id] = v; return;
  }
  id -= 1008;
  if (id < 4096){
    int s = slen[id] - 1; s = s < 0 ? 0 : (s > 47 ? 47 : s);
    idx[id] = s; return;
  }
  id -= 4096;
  if (id < 4096*252){ h32A[id] = h0[id % 252]; return; }
  id -= 4096*252;
  if (id < 4096*256){ int j = id & 255; h16A[id] = (j < 252) ? (f16)h0[j] : (f16)0.f; return; }
}

// ---------------- x transpose+convert: x16t[t][n][96] fp16, k>=76 zero ----------------
__global__ __launch_bounds__(256) void k_xt(const float* __restrict__ x,
    f16* __restrict__ x16t)
{
  int id = blockIdx.x*256 + threadIdx.x;   // 48*4096*12 total
  int c = id % 12; int rem = id / 12;
  int n = rem & 4095; int t = rem >> 12;
  const float* xp = x + ((size_t)n*48 + t)*76;
  f16x8 o;
  #pragma unroll
  for (int e = 0; e < 8; ++e){
    int k = c*8 + e;
    o[e] = (k < 76) ? (f16)xp[k] : (f16)0.f;
  }
  *(f16x8*)(x16t + ((size_t)t*4096 + n)*96 + c*8) = o;
}

// ---------------- GRU fused step ----------------
// grid (128, 8): BM=32 rows, JB=32 gate-columns; 4 waves: mi=wave&1, ji=wave>>1
__global__ __launch_bounds__(256) void k_gru(
    const f16* __restrict__ x16t, const f16* __restrict__ h16i,
    const float* __restrict__ h32i, const f16* __restrict__ BgT,
    const float* __restrict__ biasc, const int* __restrict__ idxp,
    float* __restrict__ h32o, f16* __restrict__ h16o,
    float* __restrict__ xstar, int t)
{
  int lane = threadIdx.x & 63, wv = threadIdx.x >> 6;
  int l16 = lane & 15, lq = lane >> 4;
  int mi = wv & 1, ji = wv >> 1;
  int nb = blockIdx.x * 32;
  int jb = blockIdx.y * 32;
  int row0 = nb + mi*16 + l16;
  int jcol = jb + ji*16 + l16;
  const f16* b0p = BgT + (size_t)(0*256 + jcol)*352;
  const f16* b1p = BgT + (size_t)(1*256 + jcol)*352;
  const f16* b2p = BgT + (size_t)(2*256 + jcol)*352;
  const f16* b3p = BgT + (size_t)(3*256 + jcol)*352;
  f32x4 z4 = {0.f,0.f,0.f,0.f};
  f32x4 accR = z4, accZ = z4, accI = z4, accH = z4;
  const f16* xp = x16t + ((size_t)t*4096 + row0)*96;
  const f16* hp = h16i + (size_t)row0*256;
  #pragma unroll
  for (int ks = 0; ks < 11; ++ks){
    int koff = ks*32 + lq*8;
    f16x8 a;
    if (ks < 3){
      a = *(const f16x8*)(xp + koff);
    } else {
      a = *(const f16x8*)(hp + (koff - 96));
    }
    f16x8 br = *(const f16x8*)(b0p + koff);
    f16x8 bz = *(const f16x8*)(b1p + koff);
    accR = MFMA(a, br, accR);
    accZ = MFMA(a, bz, accZ);
    if (ks < 3){
      f16x8 bi = *(const f16x8*)(b2p + koff);
      accI = MFMA(a, bi, accI);
    } else {
      f16x8 bh = *(const f16x8*)(b3p + koff);
      accH = MFMA(a, bh, accH);
    }
  }
  if (jcol < 252){
    float bR = biasc[jcol], bZ = biasc[252+jcol], bI = biasc[504+jcol], bH = biasc[756+jcol];
    #pragma unroll
    for (int r = 0; r < 4; ++r){
      int n = nb + mi*16 + lq*4 + r;
      float rr = sigm(accR[r] + bR);
      float zz = sigm(accZ[r] + bZ);
      float ng = tanh_f(accI[r] + bI + rr*(accH[r] + bH));
      float hold = h32i[(size_t)n*252 + jcol];
      float hnew = (1.f - zz)*ng + zz*hold;
      h32o[(size_t)n*252 + jcol] = hnew;
      h16o[(size_t)n*256 + jcol] = (f16)hnew;
      if (idxp[n] == t) xstar[(size_t)n*256 + jcol] = hnew;
    }
  }
}

// ---------------- x_star assembly (demo cols) + fp16 copy ----------------
__global__ __launch_bounds__(256) void k_xstar(const float* __restrict__ x_demo,
    float* __restrict__ xs32, f16* __restrict__ xs16)
{
  int id = blockIdx.x*256 + threadIdx.x;
  int n = id >> 8, c = id & 255;
  float v;
  if (c < 252) v = xs32[id];
  else v = x_demo[n*4 + (c - 252)];
  xs32[id] = v;
  xs16[id] = (f16)v;
}

// ---------------- q/k projections ----------------
// MODE 0: out = (xs@wq^T + bq) * wo[head]/8 ; MODE 1: out = xs@wk^T + bk
template<int MODE>
__global__ __launch_bounds__(256) void k_proj(const f16* __restrict__ xs16,
    const f16* __restrict__ w16, const float* __restrict__ bias,
    const float* __restrict__ wo, f16* __restrict__ out16)
{
  int lane = threadIdx.x & 63, wv = threadIdx.x >> 6;
  int l16 = lane & 15, lq = lane >> 4;
  int nb = blockIdx.x * 64;
  int ocol = blockIdx.y*64 + wv*16 + l16;
  f32x4 z4 = {0.f,0.f,0.f,0.f};
  f32x4 acc[4] = {z4,z4,z4,z4};
  #pragma unroll
  for (int ks = 0; ks < 8; ++ks){
    f16x8 b = *(const f16x8*)(w16 + (size_t)ocol*256 + ks*32 + lq*8);
    #pragma unroll
    for (int mi = 0; mi < 4; ++mi){
      f16x8 a = *(const f16x8*)(xs16 + (size_t)(nb + mi*16 + l16)*256 + ks*32 + lq*8);
      acc[mi] = MFMA(a, b, acc[mi]);
    }
  }
  float badd = bias[ocol];
  float scale = (MODE == 0) ? wo[ocol >> 6]*0.125f : 1.f;
  #pragma unroll
  for (int mi = 0; mi < 4; ++mi)
  #pragma unroll
  for (int r = 0; r < 4; ++r){
    int n = nb + mi*16 + lq*4 + r;
    float v = acc[mi][r] + badd;
    if (MODE == 0) v *= scale;
    out16[(size_t)n*256 + ocol] = (f16)v;
  }
}

// ---------------- scores GEMM (bf16 store) ----------------
__global__ __launch_bounds__(256) void k_scores(const f16* __restrict__ qf,
    const f16* __restrict__ kf, uint16_t* __restrict__ sco)
{
  int lane = threadIdx.x & 63, wv = threadIdx.x >> 6;
  int l16 = lane & 15, lq = lane >> 4;
  int nb = blockIdx.x * 64;
  int mcol = blockIdx.y*64 + wv*16 + l16;
  f32x4 z4 = {0.f,0.f,0.f,0.f};
  f32x4 acc[4] = {z4,z4,z4,z4};
  #pragma unroll
  for (int ks = 0; ks < 8; ++ks){
    f16x8 b = *(const f16x8*)(kf + (size_t)mcol*256 + ks*32 + lq*8);
    #pragma unroll
    for (int mi = 0; mi < 4; ++mi){
      f16x8 a = *(const f16x8*)(qf + (size_t)(nb + mi*16 + l16)*256 + ks*32 + lq*8);
      acc[mi] = MFMA(a, b, acc[mi]);
    }
  }
  #pragma unroll
  for (int mi = 0; mi < 4; ++mi)
  #pragma unroll
  for (int r = 0; r < 4; ++r){
    int n = nb + mi*16 + lq*4 + r;
    sco[((size_t)n << 12) + mcol] = f2bf(acc[mi][r]);
  }
}

// ---------------- fused softmax stats + flags + degrees (block per row) ----------------
__global__ __launch_bounds__(256) void k_adj(const uint16_t* __restrict__ sco,
    const float* __restrict__ mask_edge, const float* __restrict__ phip,
    uint8_t* __restrict__ flags, float* __restrict__ sadj,
    float* __restrict__ dinv, float* __restrict__ dinva)
{
  int n = blockIdx.x;
  int lane = threadIdx.x & 63, wv = threadIdx.x >> 6;
  const uint16_t* row = sco + ((size_t)n << 12);
  int base = threadIdx.x * 16;
  const uint4* p = (const uint4*)(row + base);
  uint4 w0 = p[0], w1 = p[1];
  uint32_t ws_[8] = {w0.x,w0.y,w0.z,w0.w,w1.x,w1.y,w1.z,w1.w};
  float v[16];
  #pragma unroll
  for (int i = 0; i < 8; ++i){
    v[2*i]   = bf2f((uint16_t)(ws_[i] & 0xffffu));
    v[2*i+1] = bf2f((uint16_t)(ws_[i] >> 16));
  }
  float mx = v[0];
  #pragma unroll
  for (int i = 1; i < 16; ++i) mx = fmaxf(mx, v[i]);
  #pragma unroll
  for (int o = 32; o >= 1; o >>= 1) mx = fmaxf(mx, __shfl_xor(mx, o));
  __shared__ float redA[4], redB[4], redC[4], redD[4];
  if (lane == 0) redA[wv] = mx;
  __syncthreads();
  mx = fmaxf(fmaxf(redA[0], redA[1]), fmaxf(redA[2], redA[3]));
  float s = 0.f;
  #pragma unroll
  for (int i = 0; i < 16; ++i) s += __expf(v[i] - mx);
  #pragma unroll
  for (int o = 32; o >= 1; o >>= 1) s += __shfl_xor(s, o);
  if (lane == 0) redB[wv] = s;
  __syncthreads();
  float rs = 1.f / (redB[0] + redB[1] + redB[2] + redB[3]);
  float phi = phip[0];
  uint32_t by[16]; int c0 = 0, c1 = 0;
  #pragma unroll
  for (int e = 0; e < 16; ++e){
    float a = __expf(v[e] - mx) * rs;
    int col = base + e;
    uint32_t b = (a >= phi && col != n) ? 1u : 0u;
    if (b){ if (mask_edge[((size_t)n << 12) + col] >= 0.1f) b |= 2u; }
    by[e] = b;
    c0 += (int)(b & 1u);
    c1 += (int)(b >> 1);
  }
  uint4 pk;
  pk.x = by[0]  | (by[1]  << 8) | (by[2]  << 16) | (by[3]  << 24);
  pk.y = by[4]  | (by[5]  << 8) | (by[6]  << 16) | (by[7]  << 24);
  pk.z = by[8]  | (by[9]  << 8) | (by[10] << 16) | (by[11] << 24);
  pk.w = by[12] | (by[13] << 8) | (by[14] << 16) | (by[15] << 24);
  *(uint4*)(flags + ((size_t)n << 12) + base) = pk;
  float f0 = (float)c0, f1 = (float)c1;
  #pragma unroll
  for (int o = 32; o >= 1; o >>= 1){ f0 += __shfl_xor(f0, o); f1 += __shfl_xor(f1, o); }
  if (lane == 0){ redC[wv] = f0; redD[wv] = f1; }
  __syncthreads();
  if (threadIdx.x == 0){
    float d0 = redC[0]+redC[1]+redC[2]+redC[3];
    float d1 = redD[0]+redD[1]+redD[2]+redD[3];
    sadj[n] = d0;
    dinv[n]  = rsqrtf(1.f + d0);
    dinva[n] = rsqrtf(1.f + d1);
  }
}

// ---------------- xw = xs@gcn_w ; y = dinv*xw (fp16) ----------------
__global__ __launch_bounds__(256) void k_xw_y(const f16* __restrict__ xs16,
    const f16* __restrict__ gw16, const float* __restrict__ dinv,
    const float* __restrict__ dinva, f16* __restrict__ y16, f16* __restrict__ ya16)
{
  int lane = threadIdx.x & 63, wv = threadIdx.x >> 6;
  int l16 = lane & 15, lq = lane >> 4;
  int nb = blockIdx.x * 64;
  int jcol = blockIdx.y*64 + wv*16 + l16;
  f32x4 z4 = {0.f,0.f,0.f,0.f};
  f32x4 acc[4] = {z4,z4,z4,z4};
  #pragma unroll
  for (int ks = 0; ks < 8; ++ks){
    f16x8 b = *(const f16x8*)(gw16 + (size_t)jcol*256 + ks*32 + lq*8);
    #pragma unroll
    for (int mi = 0; mi < 4; ++mi){
      f16x8 a = *(const f16x8*)(xs16 + (size_t)(nb + mi*16 + l16)*256 + ks*32 + lq*8);
      acc[mi] = MFMA(a, b, acc[mi]);
    }
  }
  #pragma unroll
  for (int mi = 0; mi < 4; ++mi)
  #pragma unroll
  for (int r = 0; r < 4; ++r){
    int n = nb + mi*16 + lq*4 + r;
    float v = acc[mi][r];
    y16[(size_t)n*256 + jcol]  = (f16)(dinv[n]*v);
    ya16[(size_t)n*256 + jcol] = (f16)(dinva[n]*v);
  }
}

// ---------------- GCN gather: parallel flag compaction, then gather ----------------
__global__ __launch_bounds__(256) void k_zgather(const uint8_t* __restrict__ flags,
    const f16* __restrict__ y16, const f16* __restrict__ ya16,
    const float* __restrict__ dinv, const float* __restrict__ dinva,
    const float* __restrict__ gcn_b, float* __restrict__ z32, float* __restrict__ za32)
{
  int n = blockIdx.x;
  int aug = blockIdx.y;
  const f16* y = aug ? ya16 : y16;
  int lane = threadIdx.x & 63, wv = threadIdx.x >> 6;
  uint4 w = ((const uint4*)(flags + ((size_t)n << 12)))[threadIdx.x];
  uint32_t bitm = aug ? 0x02020202u : 0x01010101u;
  uint32_t mm[4] = {w.x & bitm, w.y & bitm, w.z & bitm, w.w & bitm};
  int cnt = __popc(mm[0]) + __popc(mm[1]) + __popc(mm[2]) + __popc(mm[3]);
  // 2-level exclusive prefix scan of cnt over 256 threads
  int v = cnt;
  #pragma unroll
  for (int o = 1; o < 64; o <<= 1){
    int u = __shfl_up(v, o);
    if (lane >= o) v += u;
  }
  __shared__ int wsum[4];
  if (lane == 63) wsum[wv] = v;
  __syncthreads();
  int pos = v - cnt;
  #pragma unroll
  for (int i = 0; i < 4; ++i) if (i < wv) pos += wsum[i];
  int total = wsum[0] + wsum[1] + wsum[2] + wsum[3];
  __shared__ uint16_t list[4096];
  int cbase = threadIdx.x * 16;
  #pragma unroll
  for (int q = 0; q < 4; ++q){
    uint32_t m = mm[q];
    while (m){
      int b = __ffs(m) - 1;       // 0,8,16,24
      list[pos++] = (uint16_t)(cbase + q*4 + (b >> 3));
      m &= m - 1;
    }
  }
  __syncthreads();
  int j = threadIdx.x;
  float acc = (float)y[((size_t)n << 8) + j];  // self loop
  for (int i = 0; i < total; ++i){
    int m = list[i];
    acc += (float)y[((size_t)m << 8) + j];
  }
  float dv = aug ? dinva[n] : dinv[n];
  float* z = aug ? za32 : z32;
  z[((size_t)n << 8) + j] = dv*acc + gcn_b[j];
}

// ---------------- clustering: qsoft, labels, colsum ----------------
__global__ __launch_bounds__(256) void k_cluster(const float* __restrict__ xs32,
    const float* __restrict__ centers, float* __restrict__ qsoft,
    int* __restrict__ labels, float* __restrict__ colsum)
{
  int nb = blockIdx.x * 16;
  __shared__ float xs[16][256];
  __shared__ float ct[2560];   // transposed [d][k]
  __shared__ float d2s[16][10];
  __shared__ float qs[16][10];
  for (int i = threadIdx.x; i < 16*256; i += 256) xs[i >> 8][i & 255] = xs32[(size_t)nb*256 + i];
  for (int i = threadIdx.x; i < 2560; i += 256){ int k = i >> 8, d = i & 255; ct[d*10 + k] = centers[i]; }
  __syncthreads();
  if (threadIdx.x < 160){
    int r = threadIdx.x / 10, k = threadIdx.x % 10;
    float s = 0.f;
    for (int d = 0; d < 256; ++d){ float df = xs[r][d] - ct[d*10 + k]; s += df*df; }
    d2s[r][k] = s;
  }
  __syncthreads();
  if (threadIdx.x < 16){
    int r = threadIdx.x;
    float un[10]; float tot = 0.f;
    #pragma unroll
    for (int k = 0; k < 10; ++k){ un[k] = 1.f/(1.f + d2s[r][k]); tot += un[k]; }
    float inv = 1.f / tot;
    int best = 0; float bm = un[0];
    #pragma unroll
    for (int k = 1; k < 10; ++k){ if (un[k] > bm){ bm = un[k]; best = k; } }
    labels[nb + r] = best;
    #pragma unroll
    for (int k = 0; k < 10; ++k){ float q = un[k]*inv; qs[r][k] = q; qsoft[(size_t)(nb + r)*10 + k] = q; }
  }
  __syncthreads();
  if (threadIdx.x < 10){
    int k = threadIdx.x; float s = 0.f;
    #pragma unroll
    for (int r = 0; r < 16; ++r) s += qs[r][k];
    atomicAdd(&colsum[k], s);
  }
}

// ---------------- KL loss ----------------
__global__ __launch_bounds__(256) void k_kl(const float* __restrict__ qsoft,
    const float* __restrict__ colsum, float* __restrict__ klsum)
{
  int n = blockIdx.x*256 + threadIdx.x;
  float p[10]; float s = 0.f;
  #pragma unroll
  for (int k = 0; k < 10; ++k){
    float q = qsoft[(size_t)n*10 + k];
    float pu = q*q/colsum[k];
    p[k] = pu; s += pu;
  }
  float inv = 1.f/s; float kl = 0.f;
  #pragma unroll
  for (int k = 0; k < 10; ++k){
    float pk = p[k]*inv;
    float q = qsoft[(size_t)n*10 + k];
    kl += pk*__logf(pk/(q + 1e-6f));
  }
  int lane = threadIdx.x & 63, wv = threadIdx.x >> 6;
  #pragma unroll
  for (int o = 32; o >= 1; o >>= 1) kl += __shfl_xor(kl, o);
  __shared__ float red[4];
  if (lane == 0) red[wv] = kl;
  __syncthreads();
  if (threadIdx.x == 0) atomicAdd(klsum, red[0]+red[1]+red[2]+red[3]);
}

// ---------------- FFN + l2-normalize ----------------
__global__ __launch_bounds__(128) void k_ffn(const float* __restrict__ z32,
    const float* __restrict__ za32, const float* __restrict__ ffn_w,
    const float* __restrict__ ffn_b, f16* __restrict__ zn16, f16* __restrict__ zan16)
{
  int n = blockIdx.x; int aug = blockIdx.y;
  const float* z = (aug ? za32 : z32) + ((size_t)n << 8);
  __shared__ float zr[256];
  zr[threadIdx.x] = z[threadIdx.x];
  zr[threadIdx.x + 128] = z[threadIdx.x + 128];
  __syncthreads();
  int j = threadIdx.x;
  float acc = ffn_b[j];
  #pragma unroll 8
  for (int d = 0; d < 256; ++d) acc += zr[d]*ffn_w[d*128 + j];
  float ss = acc*acc;
  int lane = threadIdx.x & 63, wv = threadIdx.x >> 6;
  #pragma unroll
  for (int o = 32; o >= 1; o >>= 1) ss += __shfl_xor(ss, o);
  __shared__ float sred[2];
  if (lane == 0) sred[wv] = ss;
  __syncthreads();
  float tot = sred[0] + sred[1];
  float rn = 1.f / fmaxf(sqrtf(tot), 1e-12f);
  (aug ? zan16 : zn16)[((size_t)n << 7) + j] = (f16)(acc*rn);
}

// ---------------- contrastive loss partial sums ----------------
// grid (128, 8): 32 rows/block, 512 m per y-chunk; K=128
__global__ __launch_bounds__(256) void k_closs(const f16* __restrict__ zn,
    const f16* __restrict__ zan, const uint8_t* __restrict__ flags,
    const int* __restrict__ labels,
    float* __restrict__ rs1, float* __restrict__ rs2, float* __restrict__ rsA,
    float* __restrict__ rsC, float* __restrict__ rcC, float* __restrict__ rdI,
    float* __restrict__ rdi)
{
  int lane = threadIdx.x & 63;
  int ji = threadIdx.x >> 6;
  int l16 = lane & 15, lq = lane >> 4;
  int nb = blockIdx.x * 32;
  int mstart = blockIdx.y * 512;
  f16x8 A[2][4];
  #pragma unroll
  for (int mi = 0; mi < 2; ++mi)
  #pragma unroll
  for (int ks = 0; ks < 4; ++ks)
    A[mi][ks] = *(const f16x8*)(zn + (size_t)(nb + mi*16 + l16)*128 + ks*32 + lq*8);
  int labn[8];
  #pragma unroll
  for (int i = 0; i < 8; ++i) labn[i] = labels[nb + (i >> 2)*16 + lq*4 + (i & 3)];
  float a1[8]={}, a2[8]={}, aA[8]={}, aC[8]={}, aCc[8]={}, adI[8]={}, adi[8]={};
  for (int tile = 0; tile < 8; ++tile){
    int mcol = mstart + tile*64 + ji*16 + l16;
    int labm = labels[mcol];
    f32x4 z4 = {0.f,0.f,0.f,0.f};
    f32x4 acc1[2] = {z4, z4};
    f32x4 acc2[2] = {z4, z4};
    #pragma unroll
    for (int ks = 0; ks < 4; ++ks){
      f16x8 b1 = *(const f16x8*)(zn  + (size_t)mcol*128 + ks*32 + lq*8);
      f16x8 b2 = *(const f16x8*)(zan + (size_t)mcol*128 + ks*32 + lq*8);
      #pragma unroll
      for (int mi = 0; mi < 2; ++mi){
        acc1[mi] = MFMA(A[mi][ks], b1, acc1[mi]);
        acc2[mi] = MFMA(A[mi][ks], b2, acc2[mi]);
      }
    }
    #pragma unroll
    for (int mi = 0; mi < 2; ++mi)
    #pragma unroll
    for (int r = 0; r < 4; ++r){
      int i8 = mi*4 + r;
      int n = nb + mi*16 + lq*4 + r;
      float e1 = __expf(2.f*acc1[mi][r]);
      float e2 = __expf(2.f*acc2[mi][r]);
      uint8_t fl = flags[((size_t)n << 12) + mcol];
      a1[i8] += e1; a2[i8] += e2;
      bool adjb = (fl & 1);
      if (adjb) aA[i8] += e1;
      if (!adjb && labn[i8] == labm && n != mcol){ aC[i8] += e1; aCc[i8] += 1.f; }
      if (n == mcol){ adI[i8] += e2; adi[i8] += e1; }
    }
  }
  #pragma unroll
  for (int i = 0; i < 8; ++i){
    #pragma unroll
    for (int o = 1; o < 16; o <<= 1){
      a1[i]  += __shfl_xor(a1[i], o);  a2[i]  += __shfl_xor(a2[i], o);
      aA[i]  += __shfl_xor(aA[i], o);  aC[i]  += __shfl_xor(aC[i], o);
      aCc[i] += __shfl_xor(aCc[i], o); adI[i] += __shfl_xor(adI[i], o);
      adi[i] += __shfl_xor(adi[i], o);
    }
  }
  if (l16 == 0){
    #pragma unroll
    for (int i = 0; i < 8; ++i){
      int n = nb + (i >> 2)*16 + lq*4 + (i & 3);
      atomicAdd(&rs1[n], a1[i]);  atomicAdd(&rs2[n], a2[i]);
      atomicAdd(&rsA[n], aA[i]);  atomicAdd(&rsC[n], aC[i]);
      atomicAdd(&rcC[n], aCc[i]); atomicAdd(&rdI[n], adI[i]);
      atomicAdd(&rdi[n], adi[i]);
    }
  }
}

// ---------------- contrastive loss finalize ----------------
__global__ __launch_bounds__(256) void k_clfinal(const float* __restrict__ rs1,
    const float* __restrict__ rs2, const float* __restrict__ rsA,
    const float* __restrict__ rsC, const float* __restrict__ rcC,
    const float* __restrict__ rdI, const float* __restrict__ rdi,
    const float* __restrict__ sadj, float* __restrict__ clsum)
{
  int n = blockIdx.x*256 + threadIdx.x;
  float pos = rdI[n] + rsA[n] + rsC[n];
  float den = rs1[n] + rs2[n] - rdi[n];
  float cnt = sadj[n] + rcC[n] + 1.f;
  float v = __logf(pos/den)/cnt;
  int lane = threadIdx.x & 63, wv = threadIdx.x >> 6;
  #pragma unroll
  for (int o = 32; o >= 1; o >>= 1) v += __shfl_xor(v, o);
  __shared__ float red[4];
  if (lane == 0) red[wv] = v;
  __syncthreads();
  if (threadIdx.x == 0) atomicAdd(clsum, red[0]+red[1]+red[2]+red[3]);
}

__global__ void k_loss(const float* __restrict__ scal, float* __restrict__ out){
  out[8192] = scal[0]*(1.f/4096.f) - scal[1];
}

// ---------------- output head (wave per row) ----------------
__global__ __launch_bounds__(256) void k_outhead(const float* __restrict__ z32,
    const float* __restrict__ pre_w, const float* __restrict__ pre_b,
    float* __restrict__ out)
{
  int lane = threadIdx.x & 63, wv = threadIdx.x >> 6;
  int n = blockIdx.x*4 + wv;
  float4 zv = *(const float4*)(z32 + ((size_t)n << 8) + lane*4);
  float4 w0 = *(const float4*)(pre_w + lane*8);       // d=4L,4L+1 x {c0,c1}
  float4 w1 = *(const float4*)(pre_w + lane*8 + 4);   // d=4L+2,4L+3
  float c0 = zv.x*w0.x + zv.y*w0.z + zv.z*w1.x + zv.w*w1.z;
  float c1 = zv.x*w0.y + zv.y*w0.w + zv.z*w1.y + zv.w*w1.w;
  #pragma unroll
  for (int o = 32; o >= 1; o >>= 1){ c0 += __shfl_xor(c0, o); c1 += __shfl_xor(c1, o); }
  if (lane == 0){
    out[(size_t)n*2]     = c0 + pre_b[0];
    out[(size_t)n*2 + 1] = c1 + pre_b[1];
  }
}

// ---------------- host launch ----------------
extern "C" void kernel_launch(void* const* d_in, const int* in_sizes, int n_in,
                              void* d_out, int out_size, void* d_ws, size_t ws_size,
                              hipStream_t stream)
{
  const float* x         = (const float*)d_in[0];
  const float* x_demo    = (const float*)d_in[1];
  const int*   slen      = (const int*)d_in[2];
  const float* mask_edge = (const float*)d_in[3];
  const float* w_ih      = (const float*)d_in[4];
  const float* w_hh      = (const float*)d_in[5];
  const float* b_ih      = (const float*)d_in[6];
  const float* b_hh      = (const float*)d_in[7];
  const float* h0        = (const float*)d_in[8];
  const float* wq        = (const float*)d_in[9];
  const float* bq        = (const float*)d_in[10];
  const float* wk        = (const float*)d_in[11];
  const float* bk        = (const float*)d_in[12];
  const float* wo        = (const float*)d_in[13];
  const float* phi       = (const float*)d_in[15];
  const float* centers   = (const float*)d_in[16];
  const float* gcn_w     = (const float*)d_in[17];
  const float* gcn_b     = (const float*)d_in[18];
  const float* ffn_w     = (const float*)d_in[19];
  const float* ffn_b     = (const float*)d_in[20];
  const float* pre_w     = (const float*)d_in[21];
  const float* pre_b     = (const float*)d_in[22];
  float* out = (float*)d_out;

  size_t off = 0;
  char* base = (char*)d_ws;
  auto take = [&](size_t bytes)->void*{
    void* p = base + off;
    off += (bytes + 255) & ~(size_t)255;
    return p;
  };
  float* h32A   = (float*)take((size_t)4096*252*4);
  float* h32B   = (float*)take((size_t)4096*252*4);
  f16*   h16A   = (f16*)take((size_t)4096*256*2);
  f16*   h16B   = (f16*)take((size_t)4096*256*2);
  f16*   BgT    = (f16*)take((size_t)4*256*352*2);
  f16*   wq16   = (f16*)take((size_t)65536*2);
  f16*   wk16   = (f16*)take((size_t)65536*2);
  f16*   gw16   = (f16*)take((size_t)65536*2);
  float* biasc  = (float*)take(1008*4);
  int*   idx    = (int*)take(4096*4);
  float* xs32   = (float*)take((size_t)4096*256*4);
  f16*   xs16   = (f16*)take((size_t)4096*256*2);
  f16*   qf16   = (f16*)take((size_t)4096*256*2);
  f16*   kf16   = (f16*)take((size_t)4096*256*2);
  uint16_t* sco = (uint16_t*)take((size_t)4096*4096*2);
  uint8_t* flags= (uint8_t*)take((size_t)4096*4096);
  float* sadj   = (float*)take(4096*4);
  float* dinv   = (float*)take(4096*4);
  float* dinva  = (float*)take(4096*4);
  f16*   y16    = (f16*)take((size_t)4096*256*2);
  f16*   ya16   = (f16*)take((size_t)4096*256*2);
  float* z32    = (float*)take((size_t)4096*256*4);
  float* za32   = (float*)take((size_t)4096*256*4);
  f16*   zn16   = (f16*)take((size_t)4096*128*2);
  f16*   zan16  = (f16*)take((size_t)4096*128*2);
  float* qsoft  = (float*)take((size_t)4096*10*4);
  int*   labels = (int*)take(4096*4);
  float* colsum = (float*)take(64);
  float* scal   = (float*)take(64);         // [0]=klsum, [1]=clsum
  float* rsbuf  = (float*)take((size_t)7*4096*4);
  float* rs1 = rsbuf,        *rs2 = rsbuf + 4096, *rsA = rsbuf + 2*4096;
  float* rsC = rsbuf + 3*4096, *rcC = rsbuf + 4*4096;
  float* rdI = rsbuf + 5*4096, *rdi = rsbuf + 6*4096;

  // x16t[48][4096][96] fp16 (37.75 MB) aliases sco(33.55MB)+flags(16.7MB):
  // x16t is only live during the GRU; sco/flags are written strictly after.
  f16* x16t = (f16*)sco;

  hipMemsetAsync(h16A, 0, (size_t)4096*256*2, stream);
  hipMemsetAsync(h16B, 0, (size_t)4096*256*2, stream);
  hipMemsetAsync(colsum, 0, 64, stream);
  hipMemsetAsync(scal, 0, 64, stream);
  hipMemsetAsync(rsbuf, 0, (size_t)7*4096*4, stream);

  k_prep<<<10325, 256, 0, stream>>>(w_ih, w_hh, b_ih, b_hh, h0, slen, wq, wk, gcn_w,
                                    BgT, wq16, wk16, gw16, biasc, idx, h32A, h16A);
  k_xt<<<9216, 256, 0, stream>>>(x, x16t);

  for (int t = 0; t < 48; ++t){
    const float* hi32 = (t & 1) ? h32B : h32A;
    float*       ho32 = (t & 1) ? h32A : h32B;
    const f16*   hi16 = (t & 1) ? h16B : h16A;
    f16*         ho16 = (t & 1) ? h16A : h16B;
    k_gru<<<dim3(128, 8), 256, 0, stream>>>(x16t, hi16, hi32, BgT, biasc, idx,
                                            ho32, ho16, xs32, t);
  }
  k_xstar<<<4096, 256, 0, stream>>>(x_demo, xs32, xs16);
  k_proj<0><<<dim3(64, 4), 256, 0, stream>>>(xs16, wq16, bq, wo, qf16);
  k_proj<1><<<dim3(64, 4), 256, 0, stream>>>(xs16, wk16, bk, wo, kf16);
  k_scores<<<dim3(64, 64), 256, 0, stream>>>(qf16, kf16, sco);
  k_adj<<<4096, 256, 0, stream>>>(sco, mask_edge, phi, flags, sadj, dinv, dinva);
  k_xw_y<<<dim3(64, 4), 256, 0, stream>>>(xs16, gw16, dinv, dinva, y16, ya16);
  k_zgather<<<dim3(4096, 2), 256, 0, stream>>>(flags, y16, ya16, dinv, dinva, gcn_b, z32, za32);
  k_cluster<<<256, 256, 0, stream>>>(xs32, centers, qsoft, labels, colsum);
  k_kl<<<16, 256, 0, stream>>>(qsoft, colsum, &scal[0]);
  k_ffn<<<dim3(4096, 2), 128, 0, stream>>>(z32, za32, ffn_w, ffn_b, zn16, zan16);
  k_closs<<<dim3(128, 8), 256, 0, stream>>>(zn16, zan16, flags, labels,
                                            rs1, rs2, rsA, rsC, rcC, rdI, rdi);
  k_clfinal<<<16, 256, 0, stream>>>(rs1, rs2, rsA, rsC, rcC, rdI, rdi, sadj, &scal[1]);
  k_loss<<<1, 1, 0, stream>>>(scal, out);
  k_outhead<<<1024, 256, 0, stream>>>(z32, pre_w, pre_b, out);

  (void)in_sizes; (void)n_in; (void)out_size; (void)ws_size;
}